// Round 3
// baseline (442.074 us; speedup 1.0000x reference)
//
#include <hip/hip_runtime.h>

typedef __bf16 bf16_t;
typedef bf16_t v8bf __attribute__((ext_vector_type(8)));
typedef bf16_t v4bf __attribute__((ext_vector_type(4)));
typedef float v16f __attribute__((ext_vector_type(16)));

#define NV 1024
#define ND 256
#define NR 65536
#define BM 32

// codebook fp32 [V][D] -> cws bf16 [kt=64][d=256][ki=16]  (k = kt*16+ki)
__global__ void prep_codebook(const float* __restrict__ cb, bf16_t* __restrict__ cws) {
    int g = blockIdx.x * blockDim.x + threadIdx.x;   // 0..65535
    int e = g * 4;
#pragma unroll
    for (int ii = 0; ii < 4; ++ii, ++e) {
        int kt = e >> 12;           // / 4096
        int d  = (e >> 4) & 255;
        int ki = e & 15;
        cws[e] = (bf16_t)cb[(kt * 16 + ki) * ND + d];
    }
}

__device__ inline v4bf exp4(float4 x, float& s) {
    v4bf e;
    e[0] = (bf16_t)__expf(x.x);
    e[1] = (bf16_t)__expf(x.y);
    e[2] = (bf16_t)__expf(x.z);
    e[3] = (bf16_t)__expf(x.w);
    // sum the bf16-rounded values so normalization matches the matmul operand
    s += (float)e[0] + (float)e[1] + (float)e[2] + (float)e[3];
    return e;
}

__global__ __launch_bounds__(256, 2)
void scl_main(const float* __restrict__ logits,
              const int* __restrict__ targets,
              const float* __restrict__ cbf,     // fp32 codebook [V][D]
              const bf16_t* __restrict__ cws,    // bf16 tiled codebook
              float* __restrict__ out) {
    // 64KB: unnormalized exps, bf16, row stride 2048B, XOR-swizzled by ((r&7)<<4)
    __shared__ char sE[BM * 2048];
    __shared__ float sSum[BM];     // per-row exp sums

    const int tid  = (int)threadIdx.x;
    const int w    = tid >> 6;        // wave 0..3
    const int l    = tid & 63;        // lane
    const int brow = (int)blockIdx.x * BM;

    // ---------------- Phase A: exp + row sums ----------------
    // wave w owns rows w*8 .. w*8+7 ; lane covers cols 4l + 256j (j=0..3)
#pragma unroll 2
    for (int rr = 0; rr < 8; ++rr) {
        const int r = w * 8 + rr;
        const float4* rowp = (const float4*)(logits + (size_t)(brow + r) * NV);
        float4 x0 = rowp[l];
        float4 x1 = rowp[l + 64];
        float4 x2 = rowp[l + 128];
        float4 x3 = rowp[l + 192];
        float s = 0.f;
        v4bf e0 = exp4(x0, s);
        v4bf e1 = exp4(x1, s);
        v4bf e2 = exp4(x2, s);
        v4bf e3 = exp4(x3, s);
        char* rbase = sE + r * 2048;
        const int sw = (r & 7) << 4;
        *(v4bf*)(rbase + ((8 * l +    0) ^ sw)) = e0;
        *(v4bf*)(rbase + ((8 * l +  512) ^ sw)) = e1;
        *(v4bf*)(rbase + ((8 * l + 1024) ^ sw)) = e2;
        *(v4bf*)(rbase + ((8 * l + 1536) ^ sw)) = e3;
#pragma unroll
        for (int off = 32; off > 0; off >>= 1)
            s += __shfl_xor(s, off, 64);
        if (l == 0) sSum[r] = s;
    }
    __syncthreads();

    // ---------------- Phase B: MFMA K-loop (no barriers) ----------------
    // wave w: all 32 rows x cols [w*64, w*64+64); 32x32x16 bf16 MFMA
    const int rA  = l & 31;               // A row (= output row family)
    const int g8  = l >> 5;               // k-group 0/1
    const int swA = (rA & 7) << 4;
    const char* aBase = sE + rA * 2048;
    const int cb0 = w << 6;
    // B-frag: lane reads 8 contiguous bf16 at cws[kt][cb0 + (l&31)][g8*8]
    const bf16_t* bBase = cws + (size_t)(cb0 + (l & 31)) * 16 + g8 * 8;

    v16f acc0 = {0,0,0,0,0,0,0,0,0,0,0,0,0,0,0,0};
    v16f acc1 = {0,0,0,0,0,0,0,0,0,0,0,0,0,0,0,0};

#pragma unroll 4
    for (int kt = 0; kt < 64; ++kt) {
        const int koff = ((kt << 5) | (g8 << 4)) ^ swA;     // bytes within row
        v8bf a  = *(const v8bf*)(aBase + koff);
        v8bf b0 = *(const v8bf*)(bBase + kt * 4096);        // cols cb0..cb0+31
        v8bf b1 = *(const v8bf*)(bBase + kt * 4096 + 512);  // cols cb0+32..+63
        acc0 = __builtin_amdgcn_mfma_f32_32x32x16_bf16(a, b0, acc0, 0, 0, 0);
        acc1 = __builtin_amdgcn_mfma_f32_32x32x16_bf16(a, b1, acc1, 0, 0, 0);
    }

    // ---------------- Epilogue ----------------
    // C/D layout (verified): col = lane&31, row = (reg&3) + 8*(reg>>2) + 4*(lane>>5)
    float local = 0.f;
    const int c0 = cb0 + (l & 31);
    const int rb4 = (l >> 5) << 2;
#pragma unroll
    for (int q = 0; q < 16; ++q) {
        const int rloc = (q & 3) + ((q >> 2) << 3) + rb4;
        const int grow = brow + rloc;
        const float rs = __builtin_amdgcn_rcpf(sSum[rloc]);
        const int tgt  = targets[grow];
        const float* cr = cbf + (size_t)tgt * ND;
        float d0 = acc0[q] * rs - cr[c0];
        float d1 = acc1[q] * rs - cr[c0 + 32];
        local = fmaf(d0, d0, fmaf(d1, d1, local));
    }
#pragma unroll
    for (int off = 32; off > 0; off >>= 1)
        local += __shfl_xor(local, off, 64);
    if (l == 0)
        atomicAdd(out, local * (1.0f / (65536.0f * 256.0f)));
}

extern "C" void kernel_launch(void* const* d_in, const int* in_sizes, int n_in,
                              void* d_out, int out_size, void* d_ws, size_t ws_size,
                              hipStream_t stream) {
    const float* logits  = (const float*)d_in[0];
    const int*   targets = (const int*)d_in[1];
    const float* cbf     = (const float*)d_in[2];

    bf16_t* cws = (bf16_t*)d_ws;                        // 512 KB scratch
    float*  out = (float*)d_out;

    hipMemsetAsync(d_out, 0, sizeof(float), stream);
    prep_codebook<<<256, 256, 0, stream>>>(cbf, cws);
    scl_main<<<2048, 256, 0, stream>>>(logits, targets, cbf, cws, out);
}